// Round 10
// baseline (226.365 us; speedup 1.0000x reference)
//
#include <hip/hip_runtime.h>
#include <math.h>

#define H 64
// ws layout (floats):
//   [64..319]  64 x float4 fuse params: {base, sc0, sc1, w2}
//   [384..]    encoder partials: (eb+nb) x 64 (edge blocks first, then node)
#define WS_FUSE 64
#define WS_PART 384
#define LOG2E 1.4426950408889634f

#define PIN(x) asm volatile("" : "+v"(x))
#define PIN4(v) { PIN(v.x); PIN(v.y); PIN(v.z); PIN(v.w); }

__device__ __forceinline__ float fast_sigmoid(float x) {
    float e = exp2f(-LOG2E * x);
    return __builtin_amdgcn_rcpf(1.f + e);
}
__device__ __forceinline__ float fast_tanh(float x) {
    x = fminf(fmaxf(x, -9.f), 9.f);
    float e = exp2f((2.f * LOG2E) * x);
    return (e - 1.f) * __builtin_amdgcn_rcpf(e + 1.f);
}
__device__ __forceinline__ float4 f4fma(float s, float4 a, float4 b) {
    b.x = fmaf(s, a.x, b.x); b.y = fmaf(s, a.y, b.y);
    b.z = fmaf(s, a.z, b.z); b.w = fmaf(s, a.w, b.w); return b;
}
__device__ __forceinline__ float4 f4reluacc(float4 t, float4 a) {
    a.x += fmaxf(t.x, 0.f); a.y += fmaxf(t.y, 0.f);
    a.z += fmaxf(t.z, 0.f); a.w += fmaxf(t.w, 0.f); return a;
}
#define WREDUCE(x) { x += __shfl_xor(x, 1); x += __shfl_xor(x, 2); x += __shfl_xor(x, 4); \
                     x += __shfl_xor(x, 8); x += __shfl_xor(x, 16); x += __shfl_xor(x, 32); }

// ---------------- edge encoder: relu(X @ W + b), K=5; TR=512 ----------------
__device__ void encode_edge(const float* __restrict__ X, const float* __restrict__ Wg,
                            const float* __restrict__ bias, int nrows,
                            int blk, int nblk, float* __restrict__ out, float* __restrict__ xs)
{
    int tid = threadIdx.x, lane = tid & 63, s = tid >> 6;
    int j0 = s * 8;
    float4 wa0 = *(const float4*)(Wg + 0*H + j0), wb0 = *(const float4*)(Wg + 0*H + j0 + 4);
    float4 wa1 = *(const float4*)(Wg + 1*H + j0), wb1 = *(const float4*)(Wg + 1*H + j0 + 4);
    float4 wa2 = *(const float4*)(Wg + 2*H + j0), wb2 = *(const float4*)(Wg + 2*H + j0 + 4);
    float4 wa3 = *(const float4*)(Wg + 3*H + j0), wb3 = *(const float4*)(Wg + 3*H + j0 + 4);
    float4 wa4 = *(const float4*)(Wg + 4*H + j0), wb4 = *(const float4*)(Wg + 4*H + j0 + 4);
    float4 bia = *(const float4*)(bias + j0),     bib = *(const float4*)(bias + j0 + 4);
    PIN4(wa0) PIN4(wb0) PIN4(wa1) PIN4(wb1) PIN4(wa2) PIN4(wb2)
    PIN4(wa3) PIN4(wb3) PIN4(wa4) PIN4(wb4)
    float4 acca = {0.f,0.f,0.f,0.f}, accb = {0.f,0.f,0.f,0.f};

    int ntiles = (nrows + 511) >> 9;
    for (int tile = blk; tile < ntiles; tile += nblk) {
        long base = (long)tile << 9;
        int rem = (int)(nrows - base);
        int cnt = rem > 512 ? 512 : rem;
        int nw = cnt * 5;
        __syncthreads();
        const float* Xb = X + base * 5;
        int n4 = nw >> 2;
        for (int idx = tid; idx < n4; idx += 512) ((float4*)xs)[idx] = ((const float4*)Xb)[idx];
        for (int idx = (n4 << 2) + tid; idx < nw; idx += 512) xs[idx] = Xb[idx];
        __syncthreads();
#pragma unroll
        for (int ri = 0; ri < 8; ++ri) {
            int r = ri * 64 + lane;
            if (r < cnt) {
                float x0 = xs[r*5+0], x1 = xs[r*5+1], x2 = xs[r*5+2], x3 = xs[r*5+3], x4 = xs[r*5+4];
                float4 ta = bia, tb = bib;
                ta = f4fma(x0, wa0, ta); tb = f4fma(x0, wb0, tb);
                ta = f4fma(x1, wa1, ta); tb = f4fma(x1, wb1, tb);
                ta = f4fma(x2, wa2, ta); tb = f4fma(x2, wb2, tb);
                ta = f4fma(x3, wa3, ta); tb = f4fma(x3, wb3, tb);
                ta = f4fma(x4, wa4, ta); tb = f4fma(x4, wb4, tb);
                acca = f4reluacc(ta, acca); accb = f4reluacc(tb, accb);
            }
        }
    }
    WREDUCE(acca.x) WREDUCE(acca.y) WREDUCE(acca.z) WREDUCE(acca.w)
    WREDUCE(accb.x) WREDUCE(accb.y) WREDUCE(accb.z) WREDUCE(accb.w)
    if (lane == 0) {
        *(float4*)(out + j0) = acca;
        *(float4*)(out + j0 + 4) = accb;
    }
}

// ---------------- node encoder: K=2; TR=512 ----------------
__device__ void encode_node(const float* __restrict__ X, const float* __restrict__ Wg,
                            const float* __restrict__ bias, int nrows,
                            int blk, int nblk, float* __restrict__ out, float* __restrict__ xs)
{
    int tid = threadIdx.x, lane = tid & 63, s = tid >> 6;
    int j0 = s * 8;
    float4 wa0 = *(const float4*)(Wg + 0*H + j0), wb0 = *(const float4*)(Wg + 0*H + j0 + 4);
    float4 wa1 = *(const float4*)(Wg + 1*H + j0), wb1 = *(const float4*)(Wg + 1*H + j0 + 4);
    float4 bia = *(const float4*)(bias + j0),     bib = *(const float4*)(bias + j0 + 4);
    PIN4(wa0) PIN4(wb0) PIN4(wa1) PIN4(wb1)
    float4 acca = {0.f,0.f,0.f,0.f}, accb = {0.f,0.f,0.f,0.f};

    int ntiles = (nrows + 511) >> 9;
    for (int tile = blk; tile < ntiles; tile += nblk) {
        long base = (long)tile << 9;
        int rem = (int)(nrows - base);
        int cnt = rem > 512 ? 512 : rem;
        int nw = cnt * 2;
        __syncthreads();
        const float* Xb = X + base * 2;
        int n4 = nw >> 2;
        for (int idx = tid; idx < n4; idx += 512) ((float4*)xs)[idx] = ((const float4*)Xb)[idx];
        for (int idx = (n4 << 2) + tid; idx < nw; idx += 512) xs[idx] = Xb[idx];
        __syncthreads();
#pragma unroll
        for (int ri = 0; ri < 8; ++ri) {
            int r = ri * 64 + lane;
            if (r < cnt) {
                float x0 = xs[r*2+0], x1 = xs[r*2+1];
                float4 ta = bia, tb = bib;
                ta = f4fma(x0, wa0, ta); tb = f4fma(x0, wb0, tb);
                ta = f4fma(x1, wa1, ta); tb = f4fma(x1, wb1, tb);
                acca = f4reluacc(ta, acca); accb = f4reluacc(tb, accb);
            }
        }
    }
    WREDUCE(acca.x) WREDUCE(acca.y) WREDUCE(acca.z) WREDUCE(acca.w)
    WREDUCE(accb.x) WREDUCE(accb.y) WREDUCE(accb.z) WREDUCE(accb.w)
    if (lane == 0) {
        *(float4*)(out + j0) = acca;
        *(float4*)(out + j0 + 4) = accb;
    }
}

__global__ __launch_bounds__(512, 2)
void k_encode(const float* __restrict__ node_feats, const float* __restrict__ edge_feats,
              const float* __restrict__ node_W, const float* __restrict__ node_b,
              const float* __restrict__ edge_W, const float* __restrict__ edge_b,
              int Nn, int Ne, int eb, int nb, float* __restrict__ ws)
{
    __shared__ __align__(16) float xs[2560];   // 512 rows * 5
    int b = blockIdx.x;
    if (b < eb) {
        encode_edge(edge_feats, edge_W, edge_b, Ne, b, eb,
                    ws + WS_PART + (size_t)b * H, xs);
    } else {
        encode_node(node_feats, node_W, node_b, Nn, b - eb, nb,
                    ws + WS_PART + (size_t)b * H, xs);
    }
}

// ---------------- LSTM: 512 thr = 4 gates x 2 k-halves x 64 j; ONE barrier/step ----------------
// Every wave redundantly maintains c[j],h[j] in lane j; k-half of h comes from the
// wave's OWN lanes via v_readlane (register-only). Partials exchanged once via LDS.
__global__ __launch_bounds__(512, 1)
void k_lstm(const float* __restrict__ hist,
            const float* __restrict__ Wih, const float* __restrict__ Whh,
            const float* __restrict__ bih, const float* __restrict__ bhh,
            const float* __restrict__ W1, const float* __restrict__ b1,
            const float* __restrict__ W2,
            float inv_n, float inv_e, float inv_denom,
            int T, int eb, int nb, float* __restrict__ ws)
{
    __shared__ float p_sh[2][512];            // [parity][wave*64 + j]
    __shared__ float hist_s[608];
    __shared__ float hz[64];
    __shared__ __align__(16) float fin[1728]; // finalize scratch (8 waves)
    int tid = threadIdx.x;
    int ln = tid & 63;                        // output index j
    int wv = tid >> 6;                        // 0..7
    int g  = wv >> 1;                         // gate (i,f,g,o)
    int s  = wv & 1;                          // k-half
    int row = (g << 6) + ln;                  // gate row in Whh
    int kbu = __builtin_amdgcn_readfirstlane((tid >> 6 & 1) << 5);  // 32*s, SGPR

    // 8 named float4 = Whh[row][32s .. 32s+32): 32 weight VGPRs (proven-safe size)
    const float* wr = Whh + (size_t)row * H + kbu;
    float4 w0 = *(const float4*)(wr +  0), w1 = *(const float4*)(wr +  4);
    float4 w2 = *(const float4*)(wr +  8), w3 = *(const float4*)(wr + 12);
    float4 w4 = *(const float4*)(wr + 16), w5 = *(const float4*)(wr + 20);
    float4 w6 = *(const float4*)(wr + 24), w7 = *(const float4*)(wr + 28);
    PIN4(w0) PIN4(w1) PIN4(w2) PIN4(w3) PIN4(w4) PIN4(w5) PIN4(w6) PIN4(w7)
    // Wih·x + bias folded by the s==0 wave of each gate
    float wi0 = Wih[row*3+0], wi1 = Wih[row*3+1], wi2 = Wih[row*3+2];
    float bs  = bih[row] + bhh[row];

    for (int idx = tid; idx < T * 3; idx += 512) hist_s[idx] = hist[idx];
    float c = 0.f, h = 0.f;                   // redundant in all 8 waves
    __syncthreads();
    float x0 = hist_s[0], x1 = hist_s[1], x2 = hist_s[2];

#define RL(m) __int_as_float(__builtin_amdgcn_readlane(hi, kbu + (m)))
    for (int t = 0; t < T; ++t) {
        int hi = __float_as_int(h);
        float pa = 0.f, pb = 0.f, pc = 0.f, pd = 0.f;
        pa = fmaf(w0.x, RL(0),  pa); pb = fmaf(w0.y, RL(1),  pb);
        pc = fmaf(w0.z, RL(2),  pc); pd = fmaf(w0.w, RL(3),  pd);
        pa = fmaf(w1.x, RL(4),  pa); pb = fmaf(w1.y, RL(5),  pb);
        pc = fmaf(w1.z, RL(6),  pc); pd = fmaf(w1.w, RL(7),  pd);
        pa = fmaf(w2.x, RL(8),  pa); pb = fmaf(w2.y, RL(9),  pb);
        pc = fmaf(w2.z, RL(10), pc); pd = fmaf(w2.w, RL(11), pd);
        pa = fmaf(w3.x, RL(12), pa); pb = fmaf(w3.y, RL(13), pb);
        pc = fmaf(w3.z, RL(14), pc); pd = fmaf(w3.w, RL(15), pd);
        pa = fmaf(w4.x, RL(16), pa); pb = fmaf(w4.y, RL(17), pb);
        pc = fmaf(w4.z, RL(18), pc); pd = fmaf(w4.w, RL(19), pd);
        pa = fmaf(w5.x, RL(20), pa); pb = fmaf(w5.y, RL(21), pb);
        pc = fmaf(w5.z, RL(22), pc); pd = fmaf(w5.w, RL(23), pd);
        pa = fmaf(w6.x, RL(24), pa); pb = fmaf(w6.y, RL(25), pb);
        pc = fmaf(w6.z, RL(26), pc); pd = fmaf(w6.w, RL(27), pd);
        pa = fmaf(w7.x, RL(28), pa); pb = fmaf(w7.y, RL(29), pb);
        pc = fmaf(w7.z, RL(30), pc); pd = fmaf(w7.w, RL(31), pd);
        float p = (pa + pb) + (pc + pd);
        if (s == 0) p += fmaf(wi2, x2, fmaf(wi1, x1, fmaf(wi0, x0, bs)));
        p_sh[t & 1][(wv << 6) + ln] = p;      // stride-1 b32, conflict-free
        if (t + 1 < T) { x0 = hist_s[3*t+3]; x1 = hist_s[3*t+4]; x2 = hist_s[3*t+5]; }
        __syncthreads();                      // the ONLY barrier per step
        const float* pp = p_sh[t & 1];        // 8 stride-1 b32 reads, conflict-free
        float gi = fast_sigmoid(pp[      ln] + pp[ 64 + ln]);
        float gf = fast_sigmoid(pp[128 + ln] + pp[192 + ln]);
        float gg = fast_tanh  (pp[256 + ln] + pp[320 + ln]);
        float go = fast_sigmoid(pp[384 + ln] + pp[448 + ln]);
        c = fmaf(gf, c, gi * gg);
        h = go * fast_tanh(c);                // identical in all 8 waves
    }
    if (wv == 0) hz[ln] = h;

    // ---- finalize: reduce encoder partials, build fuse params (8 waves) ----
    {
        float* tmpe = fin;            // [8][64]
        float* tmpn = fin + 512;      // [8][64]
        float* ctx  = fin + 1024;     // [192]
        float* pt   = fin + 1216;     // [8][64]
        const float* wsp = ws + WS_PART;

        float se = 0.f;
        for (int b = wv; b < eb; b += 8) se += wsp[(size_t)b * H + ln];
        tmpe[(wv << 6) + ln] = se;
        float sn = 0.f;
        for (int b = wv; b < nb; b += 8) sn += wsp[(size_t)(eb + b) * H + ln];
        tmpn[(wv << 6) + ln] = sn;
        __syncthreads();

        if (tid < 64) {
            float s1 = 0.f, s2 = 0.f;
#pragma unroll
            for (int r = 0; r < 8; ++r) { s1 += tmpn[(r << 6) + tid]; s2 += tmpe[(r << 6) + tid]; }
            ctx[tid]       = s1 * inv_n;
            ctx[64 + tid]  = s2 * inv_e;
            ctx[128 + tid] = hz[tid];
        }
        __syncthreads();

        float p = 0.f;
#pragma unroll
        for (int kk = 0; kk < 24; ++kk) {
            int k = wv * 24 + kk;
            p = fmaf(ctx[k], W1[(size_t)k * H + ln], p);
        }
        pt[(wv << 6) + ln] = p;
        __syncthreads();

        if (tid < 64) {
            float bse = b1[tid];
#pragma unroll
            for (int r = 0; r < 8; ++r) bse += pt[(r << 6) + tid];
            float4 v;
            v.x = bse;
            v.y = W1[(size_t)192 * H + tid] * inv_denom;
            v.z = W1[(size_t)193 * H + tid] * inv_denom;
            v.w = W2[tid];
            ((float4*)(ws + WS_FUSE))[tid] = v;
        }
    }
}

// ---------------- per-pair fused MLP score, 8 pairs/thread ----------------
__global__ __launch_bounds__(256)
void k_fuse(const int* __restrict__ pairs, const float* __restrict__ fb2,
            const float* __restrict__ ws, float* __restrict__ out, int P)
{
    __shared__ __align__(16) float4 sf[H];
    int tid = threadIdx.x;
    if (tid < H) sf[tid] = ((const float4*)(ws + WS_FUSE))[tid];
    __syncthreads();

    int i0 = blockIdx.x * 2048 + tid;
    float bias = fb2[0];
    float p0[8], p1[8], sc[8];
#pragma unroll
    for (int q = 0; q < 8; ++q) {
        int i = i0 + q * 256;
        int2 pr = (i < P) ? ((const int2*)pairs)[i] : make_int2(0, 0);
        p0[q] = (float)pr.x; p1[q] = (float)pr.y; sc[q] = bias;
    }
#pragma unroll
    for (int jj = 0; jj < H; ++jj) {
        float4 v = sf[jj];
#pragma unroll
        for (int q = 0; q < 8; ++q) {
            float hh = fmaf(p1[q], v.z, fmaf(p0[q], v.y, v.x));
            sc[q] = fmaf(fmaxf(hh, 0.f), v.w, sc[q]);
        }
    }
#pragma unroll
    for (int q = 0; q < 8; ++q) {
        int i = i0 + q * 256;
        if (i < P) out[i] = sc[q];
    }
}

extern "C" void kernel_launch(void* const* d_in, const int* in_sizes, int n_in,
                              void* d_out, int out_size, void* d_ws, size_t ws_size,
                              hipStream_t stream) {
    const float* node_feats = (const float*)d_in[0];
    const float* edge_feats = (const float*)d_in[1];
    const float* hist       = (const float*)d_in[2];
    const int*   pairs      = (const int*)d_in[3];
    // d_in[4] = N scalar (== node row count)
    const float* node_W = (const float*)d_in[5];
    const float* node_b = (const float*)d_in[6];
    const float* edge_W = (const float*)d_in[7];
    const float* edge_b = (const float*)d_in[8];
    const float* Wih    = (const float*)d_in[9];
    const float* Whh    = (const float*)d_in[10];
    const float* bih    = (const float*)d_in[11];
    const float* bhh    = (const float*)d_in[12];
    const float* W1     = (const float*)d_in[13];
    const float* b1     = (const float*)d_in[14];
    const float* W2     = (const float*)d_in[15];
    const float* b2     = (const float*)d_in[16];

    int Nn = in_sizes[0] / 2;
    int Ne = in_sizes[1] / 5;
    int T  = in_sizes[2] / 3;
    int P  = in_sizes[3] / 2;

    // 960 + 64 = 1024 blocks of 512 thr -> 4 blocks/CU (latency hiding for staging)
    int eb = 960, nb = 64;
    while ((size_t)(WS_PART + (eb + nb) * H) * sizeof(float) > ws_size && eb > 8) {
        eb >>= 1; if (nb > 8) nb >>= 1;
    }

    float inv_n = (float)(1.0 / (double)Nn);
    float inv_e = (float)(1.0 / (double)Ne);
    float denomf = (float)(Nn - 1) + 1e-9f;
    float inv_denom = 1.0f / denomf;

    float* ws = (float*)d_ws;

    k_encode<<<eb + nb, 512, 0, stream>>>(
        node_feats, edge_feats, node_W, node_b, edge_W, edge_b,
        Nn, Ne, eb, nb, ws);

    k_lstm<<<1, 512, 0, stream>>>(
        hist, Wih, Whh, bih, bhh, W1, b1, W2,
        inv_n, inv_e, inv_denom, T, eb, nb, ws);

    int blocksC = (P + 2047) / 2048;
    k_fuse<<<blocksC, 256, 0, stream>>>(pairs, b2, ws, (float*)d_out, P);
}